// Round 5
// baseline (28.161 us; speedup 1.0000x reference)
//
#include <hip/hip_runtime.h>
#include <math.h>

// Tiny MLP: 6 -> 8 (relu) -> 4 (relu) -> 2 (relu) -> 1, then softplus.
// R1: native __expf/__logf transcendentals (kept).
// R4: software-pipelined — 4 quads (16 rows) per thread, double-buffered
//     loads so quad n+1's 6 float4 loads are in flight while quad n's
//     ~450 VALU instructions execute. Removes the wave-phase burst stall
//     that made VALU time additive with memory time.

typedef float v4f __attribute__((ext_vector_type(4)));

__device__ __forceinline__ float softplus_fast(float z) {
    float e = __expf(-fabsf(z));
    return fmaxf(z, 0.0f) + __logf(1.0f + e);
}

__device__ __forceinline__ void load_quad(const v4f* __restrict__ xin,
                                          size_t q, v4f b[6]) {
    const v4f* p = xin + q * 6;
    b[0] = p[0]; b[1] = p[1]; b[2] = p[2];
    b[3] = p[3]; b[4] = p[4]; b[5] = p[5];
}

__device__ __forceinline__ v4f compute_quad(
    const v4f b[6],
    const float* __restrict__ W1, const float* __restrict__ b1,
    const float* __restrict__ W7, const float* __restrict__ b7,
    const float* __restrict__ W8, const float* __restrict__ b8,
    const float* __restrict__ W9, const float* __restrict__ b9)
{
    float xr[4][6];
    xr[0][0]=b[0].x; xr[0][1]=b[0].y; xr[0][2]=b[0].z; xr[0][3]=b[0].w; xr[0][4]=b[1].x; xr[0][5]=b[1].y;
    xr[1][0]=b[1].z; xr[1][1]=b[1].w; xr[1][2]=b[2].x; xr[1][3]=b[2].y; xr[1][4]=b[2].z; xr[1][5]=b[2].w;
    xr[2][0]=b[3].x; xr[2][1]=b[3].y; xr[2][2]=b[3].z; xr[2][3]=b[3].w; xr[2][4]=b[4].x; xr[2][5]=b[4].y;
    xr[3][0]=b[4].z; xr[3][1]=b[4].w; xr[3][2]=b[5].x; xr[3][3]=b[5].y; xr[3][4]=b[5].z; xr[3][5]=b[5].w;

    v4f res;
    float out4[4];
    #pragma unroll
    for (int r = 0; r < 4; ++r) {
        float h1[8];
        #pragma unroll
        for (int j = 0; j < 8; ++j) {
            float acc = b1[j];
            #pragma unroll
            for (int k = 0; k < 6; ++k) acc = fmaf(W1[j * 6 + k], xr[r][k], acc);
            h1[j] = fmaxf(acc, 0.0f);
        }
        float h7[4];
        #pragma unroll
        for (int j = 0; j < 4; ++j) {
            float acc = b7[j];
            #pragma unroll
            for (int k = 0; k < 8; ++k) acc = fmaf(W7[j * 8 + k], h1[k], acc);
            h7[j] = fmaxf(acc, 0.0f);
        }
        float h8[2];
        #pragma unroll
        for (int j = 0; j < 2; ++j) {
            float acc = b8[j];
            #pragma unroll
            for (int k = 0; k < 4; ++k) acc = fmaf(W8[j * 4 + k], h7[k], acc);
            h8[j] = fmaxf(acc, 0.0f);
        }
        float z = fmaf(W9[0], h8[0], fmaf(W9[1], h8[1], b9[0]));
        out4[r] = softplus_fast(z);
    }
    res.x = out4[0]; res.y = out4[1]; res.z = out4[2]; res.w = out4[3];
    return res;
}

__global__ __launch_bounds__(256) void encoder_mlp_kernel(
    const float* __restrict__ x,
    const float* __restrict__ W1, const float* __restrict__ b1,
    const float* __restrict__ W7, const float* __restrict__ b7,
    const float* __restrict__ W8, const float* __restrict__ b8,
    const float* __restrict__ W9, const float* __restrict__ b9,
    float* __restrict__ out, int n_quads)
{
    const int t = blockIdx.x * blockDim.x + threadIdx.x;
    const size_t nthreads = (size_t)gridDim.x * blockDim.x;  // quad stride
    const v4f* xin = reinterpret_cast<const v4f*>(x);
    v4f* outv = reinterpret_cast<v4f*>(out);

    size_t q0 = (size_t)t;
    size_t q1 = q0 + nthreads;
    size_t q2 = q1 + nthreads;
    size_t q3 = q2 + nthreads;

    v4f bufA[6], bufB[6];

    if (q0 < (size_t)n_quads) load_quad(xin, q0, bufA);
    if (q1 < (size_t)n_quads) load_quad(xin, q1, bufB);

    if (q0 < (size_t)n_quads)
        outv[q0] = compute_quad(bufA, W1, b1, W7, b7, W8, b8, W9, b9);

    if (q2 < (size_t)n_quads) load_quad(xin, q2, bufA);
    if (q1 < (size_t)n_quads)
        outv[q1] = compute_quad(bufB, W1, b1, W7, b7, W8, b8, W9, b9);

    if (q3 < (size_t)n_quads) load_quad(xin, q3, bufB);
    if (q2 < (size_t)n_quads)
        outv[q2] = compute_quad(bufA, W1, b1, W7, b7, W8, b8, W9, b9);

    if (q3 < (size_t)n_quads)
        outv[q3] = compute_quad(bufB, W1, b1, W7, b7, W8, b8, W9, b9);
}

extern "C" void kernel_launch(void* const* d_in, const int* in_sizes, int n_in,
                              void* d_out, int out_size, void* d_ws, size_t ws_size,
                              hipStream_t stream) {
    const float* x  = (const float*)d_in[0];
    const float* W1 = (const float*)d_in[1];
    const float* b1 = (const float*)d_in[2];
    const float* W7 = (const float*)d_in[3];
    const float* b7 = (const float*)d_in[4];
    const float* W8 = (const float*)d_in[5];
    const float* b8 = (const float*)d_in[6];
    const float* W9 = (const float*)d_in[7];
    const float* b9 = (const float*)d_in[8];
    float* out = (float*)d_out;

    const int n_rows  = in_sizes[0] / 6;     // 4194304
    const int n_quads = (n_rows + 3) / 4;    // 1048576 (rows % 4 == 0 here)

    const int block = 256;
    const int quads_per_thread = 4;
    const int n_threads = (n_quads + quads_per_thread - 1) / quads_per_thread;
    const int grid = (n_threads + block - 1) / block;   // 1024 blocks

    encoder_mlp_kernel<<<grid, block, 0, stream>>>(
        x, W1, b1, W7, b7, W8, b8, W9, b9, out, n_quads);
}